// Round 5
// baseline (178.578 us; speedup 1.0000x reference)
//
#include <hip/hip_runtime.h>
#include <hip/hip_bf16.h>

#define EPSF 1e-10f

typedef short bf16x8 __attribute__((ext_vector_type(8)));
typedef float f32x4  __attribute__((ext_vector_type(4)));
typedef unsigned short u16x8 __attribute__((ext_vector_type(8)));

__device__ __forceinline__ unsigned short f2bf(float f) {
    unsigned int u = __builtin_bit_cast(unsigned int, f);
    u += 0x7fffu + ((u >> 16) & 1u);   // round-to-nearest-even
    return (unsigned short)(u >> 16);
}
__device__ __forceinline__ float b2f(unsigned short h) {
    unsigned int u = (unsigned int)h << 16;
    return __builtin_bit_cast(float, u);
}

__device__ __forceinline__ void gload16(const void* g, void* l) {
    __builtin_amdgcn_global_load_lds(
        (const __attribute__((address_space(1))) void*)g,
        (__attribute__((address_space(3))) void*)l, 16, 0, 0);
}

// ---------------------------------------------------------------------------
// Pass 1: fold rsqrt(rowsum+eps) into bf16 copy of H; bf16 per-block col
// partials. 512 blocks x 16 rows, loads pipelined across a raw s_barrier.
// Thread t owns cols {j*2048 + t*8 .. +7} (8 consecutive) -> 16B stores.
// ---------------------------------------------------------------------------
__global__ __launch_bounds__(256) void deg_convert(const float* __restrict__ H,
                                                   unsigned short* __restrict__ Hb,
                                                   unsigned short* __restrict__ colpart) {
    const int t    = threadIdx.x;
    const int b    = blockIdx.x;          // 512
    const int r0   = b * 16;
    const int lane = t & 63;
    const int wid  = t >> 6;
    __shared__ float wsum[2][4];

    float ca[32];
#pragma unroll
    for (int i = 0; i < 32; ++i) ca[i] = 0.f;

    float4 cur[8], nxt[8];
    {
        const float4* row = (const float4*)(H + (size_t)r0 * 8192);
#pragma unroll
        for (int j = 0; j < 4; ++j) {
            cur[j * 2 + 0] = row[j * 512 + t * 2 + 0];
            cur[j * 2 + 1] = row[j * 512 + t * 2 + 1];
        }
    }

    for (int r = 0; r < 16; ++r) {
        if (r < 15) {
            const float4* row = (const float4*)(H + (size_t)(r0 + r + 1) * 8192);
#pragma unroll
            for (int j = 0; j < 4; ++j) {
                nxt[j * 2 + 0] = row[j * 512 + t * 2 + 0];
                nxt[j * 2 + 1] = row[j * 512 + t * 2 + 1];
            }
        }
        float rs = 0.f;
#pragma unroll
        for (int j = 0; j < 8; ++j) {
            ca[j * 4 + 0] += cur[j].x; ca[j * 4 + 1] += cur[j].y;
            ca[j * 4 + 2] += cur[j].z; ca[j * 4 + 3] += cur[j].w;
            rs += (cur[j].x + cur[j].y) + (cur[j].z + cur[j].w);
        }
#pragma unroll
        for (int off = 32; off; off >>= 1) rs += __shfl_down(rs, off, 64);
        if (lane == 0) wsum[r & 1][wid] = rs;
        asm volatile("s_waitcnt lgkmcnt(0)" ::: "memory");
        __builtin_amdgcn_s_barrier();            // raw: nxt loads stay in flight
        asm volatile("" ::: "memory");
        const float s = rsqrtf(((wsum[r & 1][0] + wsum[r & 1][1]) +
                                (wsum[r & 1][2] + wsum[r & 1][3])) + EPSF);
        unsigned short* hrow = Hb + (size_t)(r0 + r) * 8192;
#pragma unroll
        for (int j = 0; j < 4; ++j) {
            u16x8 o;
            o[0] = f2bf(cur[j * 2 + 0].x * s); o[1] = f2bf(cur[j * 2 + 0].y * s);
            o[2] = f2bf(cur[j * 2 + 0].z * s); o[3] = f2bf(cur[j * 2 + 0].w * s);
            o[4] = f2bf(cur[j * 2 + 1].x * s); o[5] = f2bf(cur[j * 2 + 1].y * s);
            o[6] = f2bf(cur[j * 2 + 1].z * s); o[7] = f2bf(cur[j * 2 + 1].w * s);
            *(u16x8*)&hrow[j * 2048 + t * 8] = o;
        }
#pragma unroll
        for (int j = 0; j < 8; ++j) cur[j] = nxt[j];
    }

    unsigned short* cp = colpart + (size_t)b * 8192;
#pragma unroll
    for (int j = 0; j < 4; ++j) {
        u16x8 o;
#pragma unroll
        for (int i = 0; i < 8; ++i) o[i] = f2bf(ca[j * 8 + i]);
        *(u16x8*)&cp[j * 2048 + t * 8] = o;
    }
}

// ---------------------------------------------------------------------------
// Fused: blocks [0,256) reduce bf16 colpart -> de_inv; [256,1280) Fbt=bf16(F^T).
// ---------------------------------------------------------------------------
__global__ __launch_bounds__(256) void fin_fbt(const unsigned short* __restrict__ colpart,
                                               const float* __restrict__ F,
                                               float* __restrict__ de_inv,
                                               unsigned short* __restrict__ Fbt) {
    const int b = blockIdx.x;
    if (b < 256) {
        __shared__ float red[8][32];
        const int cl = threadIdx.x & 31;
        const int rg = threadIdx.x >> 5;
        const int col = b * 32 + cl;
        float s = 0.f;
#pragma unroll 4
        for (int rr = 0; rr < 64; ++rr)
            s += b2f(colpart[(size_t)(rg * 64 + rr) * 8192 + col]);
        red[rg][cl] = s;
        __syncthreads();
        if (rg == 0) {
            float tot = 0.f;
#pragma unroll
            for (int g = 0; g < 8; ++g) tot += red[g][cl];
            de_inv[col] = 1.f / (tot + EPSF);
        }
    } else {
        const int idx = (b - 256) * 256 + threadIdx.x;   // 262144
        const int d   = idx & 127;
        const int n0  = (idx >> 7) * 4;
        ushort4 o;
        o.x = f2bf(F[(size_t)(n0 + 0) * 128 + d]);
        o.y = f2bf(F[(size_t)(n0 + 1) * 128 + d]);
        o.z = f2bf(F[(size_t)(n0 + 2) * 128 + d]);
        o.w = f2bf(F[(size_t)(n0 + 3) * 128 + d]);
        *(ushort4*)&Fbt[(size_t)d * 8192 + n0] = o;
    }
}

// ---------------------------------------------------------------------------
// Split-K GEMM on bf16 Hb, 2-phase double-buffered.  BM=64, BN=128, BK=64.
// C[8192][128] = A @ B, K = 8192 split 4 ways -> grid (128, 4), 2 blocks/CU.
//   TRANS=1 (GEMM1): A[e][k] = Hb[k][e]  (reg-prefetch scalar cols -> ds_write)
//   TRANS=0 (GEMM2): A[n][k] = Hb[n][k]  (global_load_lds)
//   B always global_load_lds.  Bt is [128][8192] bf16 (k-contiguous).
// LDS layout: [rows][8 chunks x 16B]; slot s of row r holds k-chunk s^(r&7);
// frag read at kchunk kc uses slot kc^(r&7).
// ---------------------------------------------------------------------------
template <int TRANS>
__global__ __launch_bounds__(256) void gemm_sk(const unsigned short* __restrict__ Hb,
                                               const unsigned short* __restrict__ Bt,
                                               float* __restrict__ part) {
    __shared__ alignas(16) unsigned short As[2][4096];   // 64 rows x 64 k
    __shared__ alignas(16) unsigned short Bs[2][8192];   // 128 rows x 64 k

    const int t    = threadIdx.x;
    const int lane = t & 63;
    const int wid  = t >> 6;
    const int wr   = (wid >> 1) * 32;            // wave tile 32x64
    const int wc   = (wid & 1) * 64;
    const size_t mbase = (size_t)blockIdx.x * 64;
    const int kbase = blockIdx.y * 2048;

    const int rloc8 = lane >> 3;                 // 0..7
    const int schnk = (lane & 7) ^ rloc8;        // pre-swizzled source chunk
    const int c  = t & 63;                       // TRANS=1 A column (edge)
    const int kq = t >> 6;                       // 0..3

    f32x4 acc[2][4];
#pragma unroll
    for (int m = 0; m < 2; ++m)
#pragma unroll
        for (int n = 0; n < 4; ++n)
#pragma unroll
            for (int i = 0; i < 4; ++i) acc[m][n][i] = 0.f;

    auto stageB = [&](int p, int k0) {
#pragma unroll
        for (int q = 0; q < 4; ++q) {
            const int i = wid * 4 + q;           // 0..15
            gload16(Bt + (size_t)(i * 8 + rloc8) * 8192 + k0 + schnk * 8,
                    (char*)Bs[p] + i * 1024);
        }
    };
    auto stageA0 = [&](int p, int k0) {
#pragma unroll
        for (int q = 0; q < 2; ++q) {
            const int i = wid * 2 + q;           // 0..7
            gload16(Hb + (mbase + i * 8 + rloc8) * 8192 + k0 + schnk * 8,
                    (char*)As[p] + i * 1024);
        }
    };
    auto loadA1 = [&](int k0, ushort4* r) {
        const unsigned short* base = Hb + mbase + c;
#pragma unroll
        for (int j = 0; j < 4; ++j) {
            const int kk = k0 + kq * 16 + j * 4;
            r[j].x = base[(size_t)(kk + 0) * 8192];
            r[j].y = base[(size_t)(kk + 1) * 8192];
            r[j].z = base[(size_t)(kk + 2) * 8192];
            r[j].w = base[(size_t)(kk + 3) * 8192];
        }
    };
    auto writeA1 = [&](int p, const ushort4* r) {
#pragma unroll
        for (int j = 0; j < 4; ++j) {
            const int ch = kq * 2 + (j >> 1);
            *(ushort4*)((char*)As[p] + c * 128 + ((ch ^ (c & 7)) << 4) + (j & 1) * 8) = r[j];
        }
    };
    auto compute = [&](int p) {
        const char* asb = (const char*)As[p];
        const char* bsb = (const char*)Bs[p];
#pragma unroll
        for (int ks = 0; ks < 2; ++ks) {
            const int kch = ks * 4 + (lane >> 4);
            bf16x8 a[2], b[4];
#pragma unroll
            for (int m = 0; m < 2; ++m) {
                const int row = wr + m * 16 + (lane & 15);
                a[m] = *(const bf16x8*)(asb + row * 128 + ((kch ^ (row & 7)) << 4));
            }
#pragma unroll
            for (int n = 0; n < 4; ++n) {
                const int row = wc + n * 16 + (lane & 15);
                b[n] = *(const bf16x8*)(bsb + row * 128 + ((kch ^ (row & 7)) << 4));
            }
#pragma unroll
            for (int m = 0; m < 2; ++m)
#pragma unroll
                for (int n = 0; n < 4; ++n)
                    acc[m][n] = __builtin_amdgcn_mfma_f32_16x16x32_bf16(a[m], b[n], acc[m][n], 0, 0, 0);
        }
    };

    if (TRANS == 0) {
        stageB(0, kbase);
        stageA0(0, kbase);
        for (int tt = 0; tt < 32; ++tt) {
            const int p = tt & 1;
            if (tt < 31) {
                stageB(p ^ 1, kbase + (tt + 1) * 64);
                stageA0(p ^ 1, kbase + (tt + 1) * 64);
                asm volatile("s_waitcnt vmcnt(6)" ::: "memory");
            } else {
                asm volatile("s_waitcnt vmcnt(0)" ::: "memory");
            }
            __builtin_amdgcn_s_barrier();
            asm volatile("" ::: "memory");
            compute(p);
            asm volatile("s_waitcnt lgkmcnt(0)" ::: "memory");
            __builtin_amdgcn_s_barrier();
            asm volatile("" ::: "memory");
        }
    } else {
        ushort4 rA[4], rB2[4];
        stageB(0, kbase);
        loadA1(kbase, rA);
        for (int tt = 0; tt < 32; tt += 2) {
            // ---- tile tt (buffers 0) ----
            stageB(1, kbase + (tt + 1) * 64);
            loadA1(kbase + (tt + 1) * 64, rB2);
            writeA1(0, rA);        // auto-wait on rA => older B(tt) also landed
            asm volatile("s_waitcnt vmcnt(20) lgkmcnt(0)" ::: "memory");
            __builtin_amdgcn_s_barrier();
            asm volatile("" ::: "memory");
            compute(0);
            asm volatile("s_waitcnt lgkmcnt(0)" ::: "memory");
            __builtin_amdgcn_s_barrier();
            asm volatile("" ::: "memory");
            // ---- tile tt+1 (buffers 1) ----
            if (tt + 2 < 32) {
                stageB(0, kbase + (tt + 2) * 64);
                loadA1(kbase + (tt + 2) * 64, rA);
                writeA1(1, rB2);
                asm volatile("s_waitcnt vmcnt(20) lgkmcnt(0)" ::: "memory");
            } else {
                writeA1(1, rB2);
                asm volatile("s_waitcnt vmcnt(0) lgkmcnt(0)" ::: "memory");
            }
            __builtin_amdgcn_s_barrier();
            asm volatile("" ::: "memory");
            compute(1);
            asm volatile("s_waitcnt lgkmcnt(0)" ::: "memory");
            __builtin_amdgcn_s_barrier();
            asm volatile("" ::: "memory");
        }
    }

    float* po = part + ((size_t)blockIdx.y * 8192 + mbase) * 128;
#pragma unroll
    for (int m = 0; m < 2; ++m)
#pragma unroll
        for (int n = 0; n < 4; ++n)
#pragma unroll
            for (int r = 0; r < 4; ++r) {
                const int row = wr + m * 16 + (lane >> 4) * 4 + r;
                const int col = wc + n * 16 + (lane & 15);
                po[(size_t)row * 128 + col] = acc[m][n][r];
            }
}

// ---------------------------------------------------------------------------
// Reduce 4 split-K partials of GEMM1, scale by de_inv, write X2t[d][e] bf16.
// ---------------------------------------------------------------------------
__global__ __launch_bounds__(256) void reduce1(const float* __restrict__ part,
                                               const float* __restrict__ de_inv,
                                               unsigned short* __restrict__ X2t) {
    const int idx = blockIdx.x * 256 + threadIdx.x;   // 262144
    const int d   = idx & 127;
    const int e0  = (idx >> 7) * 4;
    ushort4 o;
#pragma unroll
    for (int i = 0; i < 4; ++i) {
        const size_t base = (size_t)(e0 + i) * 128 + d;
        float s = 0.f;
#pragma unroll
        for (int sk = 0; sk < 4; ++sk) s += part[base + (size_t)sk * 1048576];
        ((unsigned short*)&o)[i] = f2bf(s * de_inv[e0 + i]);
    }
    *(ushort4*)&X2t[(size_t)d * 8192 + e0] = o;
}

// ---------------------------------------------------------------------------
// Reduce 4 split-K partials of GEMM2 -> fp32 output (dv_is already folded).
// ---------------------------------------------------------------------------
__global__ __launch_bounds__(256) void reduce2(const float* __restrict__ part,
                                               float* __restrict__ out) {
    const int idx = blockIdx.x * 256 + threadIdx.x;   // 262144, float4 each
    const f32x4* p4 = (const f32x4*)part;
    f32x4 s = p4[idx];
#pragma unroll
    for (int sk = 1; sk < 4; ++sk) s += p4[idx + sk * 262144];
    ((f32x4*)out)[idx] = s;
}

// ---------------------------------------------------------------------------
// Workspace layout (bytes):
//   [0,        16777216)   split-K partials fp32 [4][8192][128]  (16 MB)
//                          (first 8 MB aliased as colpart bf16 [512][8192],
//                           dead after fin_fbt)
//   [16777216, +32768)     de_inv
//   [16809984, +2097152)   Fbt bf16 [128][8192]
//   [18907136, +2097152)   X2t bf16 [128][8192]
//   [21004288, +134217728) Hb  bf16 [8192][8192]  (dv_is-scaled)
// total ~148 MB
// ---------------------------------------------------------------------------
extern "C" void kernel_launch(void* const* d_in, const int* in_sizes, int n_in,
                              void* d_out, int out_size, void* d_ws, size_t ws_size,
                              hipStream_t stream) {
    const float* H = (const float*)d_in[0];
    const float* F = (const float*)d_in[1];
    float* out = (float*)d_out;
    char* ws = (char*)d_ws;

    float* part            = (float*)(ws);
    unsigned short* colpart= (unsigned short*)(ws);
    float* de_inv          = (float*)(ws + 16777216);
    unsigned short* Fbt    = (unsigned short*)(ws + 16809984);
    unsigned short* X2t    = (unsigned short*)(ws + 18907136);
    unsigned short* Hb     = (unsigned short*)(ws + 21004288);

    deg_convert <<<512, 256, 0, stream>>>(H, Hb, colpart);
    fin_fbt     <<<1280, 256, 0, stream>>>(colpart, F, de_inv, Fbt);
    gemm_sk<1>  <<<dim3(128, 4), 256, 0, stream>>>(Hb, Fbt, part);
    reduce1     <<<1024, 256, 0, stream>>>(part, de_inv, X2t);
    gemm_sk<0>  <<<dim3(128, 4), 256, 0, stream>>>(Hb, X2t, part);
    reduce2     <<<1024, 256, 0, stream>>>(part, out);
}

// Round 6
// 164.013 us; speedup vs baseline: 1.0888x; 1.0888x over previous
//
#include <hip/hip_runtime.h>
#include <hip/hip_bf16.h>

#define EPSF 1e-10f

typedef short bf16x8 __attribute__((ext_vector_type(8)));
typedef float f32x4  __attribute__((ext_vector_type(4)));
typedef unsigned short u16x8 __attribute__((ext_vector_type(8)));

__device__ __forceinline__ unsigned short f2bf(float f) {
    unsigned int u = __builtin_bit_cast(unsigned int, f);
    u += 0x7fffu + ((u >> 16) & 1u);   // round-to-nearest-even
    return (unsigned short)(u >> 16);
}
__device__ __forceinline__ float b2f(unsigned short h) {
    unsigned int u = (unsigned int)h << 16;
    return __builtin_bit_cast(float, u);
}

__device__ __forceinline__ void gload16(const void* g, void* l) {
    __builtin_amdgcn_global_load_lds(
        (const __attribute__((address_space(1))) void*)g,
        (__attribute__((address_space(3))) void*)l, 16, 0, 0);
}

// ---------------------------------------------------------------------------
// Pass 1: fold rsqrt(rowsum+eps) into bf16 copy of H; bf16 per-block col
// partials. 512 blocks x 16 rows, loads pipelined across a raw s_barrier.
// Thread t owns cols {j*2048 + t*8 .. +7} (8 consecutive) -> 16B stores.
// ---------------------------------------------------------------------------
__global__ __launch_bounds__(256) void deg_convert(const float* __restrict__ H,
                                                   unsigned short* __restrict__ Hb,
                                                   unsigned short* __restrict__ colpart) {
    const int t    = threadIdx.x;
    const int b    = blockIdx.x;          // 512
    const int r0   = b * 16;
    const int lane = t & 63;
    const int wid  = t >> 6;
    __shared__ float wsum[2][4];

    float ca[32];
#pragma unroll
    for (int i = 0; i < 32; ++i) ca[i] = 0.f;

    float4 cur[8], nxt[8];
    {
        const float4* row = (const float4*)(H + (size_t)r0 * 8192);
#pragma unroll
        for (int j = 0; j < 4; ++j) {
            cur[j * 2 + 0] = row[j * 512 + t * 2 + 0];
            cur[j * 2 + 1] = row[j * 512 + t * 2 + 1];
        }
    }

    for (int r = 0; r < 16; ++r) {
        if (r < 15) {
            const float4* row = (const float4*)(H + (size_t)(r0 + r + 1) * 8192);
#pragma unroll
            for (int j = 0; j < 4; ++j) {
                nxt[j * 2 + 0] = row[j * 512 + t * 2 + 0];
                nxt[j * 2 + 1] = row[j * 512 + t * 2 + 1];
            }
        }
        float rs = 0.f;
#pragma unroll
        for (int j = 0; j < 8; ++j) {
            ca[j * 4 + 0] += cur[j].x; ca[j * 4 + 1] += cur[j].y;
            ca[j * 4 + 2] += cur[j].z; ca[j * 4 + 3] += cur[j].w;
            rs += (cur[j].x + cur[j].y) + (cur[j].z + cur[j].w);
        }
#pragma unroll
        for (int off = 32; off; off >>= 1) rs += __shfl_down(rs, off, 64);
        if (lane == 0) wsum[r & 1][wid] = rs;
        asm volatile("s_waitcnt lgkmcnt(0)" ::: "memory");
        __builtin_amdgcn_s_barrier();            // raw: nxt loads stay in flight
        asm volatile("" ::: "memory");
        const float s = rsqrtf(((wsum[r & 1][0] + wsum[r & 1][1]) +
                                (wsum[r & 1][2] + wsum[r & 1][3])) + EPSF);
        unsigned short* hrow = Hb + (size_t)(r0 + r) * 8192;
#pragma unroll
        for (int j = 0; j < 4; ++j) {
            u16x8 o;
            o[0] = f2bf(cur[j * 2 + 0].x * s); o[1] = f2bf(cur[j * 2 + 0].y * s);
            o[2] = f2bf(cur[j * 2 + 0].z * s); o[3] = f2bf(cur[j * 2 + 0].w * s);
            o[4] = f2bf(cur[j * 2 + 1].x * s); o[5] = f2bf(cur[j * 2 + 1].y * s);
            o[6] = f2bf(cur[j * 2 + 1].z * s); o[7] = f2bf(cur[j * 2 + 1].w * s);
            *(u16x8*)&hrow[j * 2048 + t * 8] = o;
        }
#pragma unroll
        for (int j = 0; j < 8; ++j) cur[j] = nxt[j];
    }

    unsigned short* cp = colpart + (size_t)b * 8192;
#pragma unroll
    for (int j = 0; j < 4; ++j) {
        u16x8 o;
#pragma unroll
        for (int i = 0; i < 8; ++i) o[i] = f2bf(ca[j * 8 + i]);
        *(u16x8*)&cp[j * 2048 + t * 8] = o;
    }
}

// ---------------------------------------------------------------------------
// Fused: blocks [0,256) reduce bf16 colpart -> de_inv; [256,1280) Fbt=bf16(F^T).
// ---------------------------------------------------------------------------
__global__ __launch_bounds__(256) void fin_fbt(const unsigned short* __restrict__ colpart,
                                               const float* __restrict__ F,
                                               float* __restrict__ de_inv,
                                               unsigned short* __restrict__ Fbt) {
    const int b = blockIdx.x;
    if (b < 256) {
        __shared__ float red[8][32];
        const int cl = threadIdx.x & 31;
        const int rg = threadIdx.x >> 5;
        const int col = b * 32 + cl;
        float s = 0.f;
#pragma unroll 4
        for (int rr = 0; rr < 64; ++rr)
            s += b2f(colpart[(size_t)(rg * 64 + rr) * 8192 + col]);
        red[rg][cl] = s;
        __syncthreads();
        if (rg == 0) {
            float tot = 0.f;
#pragma unroll
            for (int g = 0; g < 8; ++g) tot += red[g][cl];
            de_inv[col] = 1.f / (tot + EPSF);
        }
    } else {
        const int idx = (b - 256) * 256 + threadIdx.x;   // 262144
        const int d   = idx & 127;
        const int n0  = (idx >> 7) * 4;
        ushort4 o;
        o.x = f2bf(F[(size_t)(n0 + 0) * 128 + d]);
        o.y = f2bf(F[(size_t)(n0 + 1) * 128 + d]);
        o.z = f2bf(F[(size_t)(n0 + 2) * 128 + d]);
        o.w = f2bf(F[(size_t)(n0 + 3) * 128 + d]);
        *(ushort4*)&Fbt[(size_t)d * 8192 + n0] = o;
    }
}

// ---------------------------------------------------------------------------
// Split-K GEMM on bf16 Hb, 2-phase double-buffered.  BM=128, BN=128, BK=64.
// C[8192][128] = A @ B, K = 8192 split 8 ways -> grid (64, 8), 2 blocks/CU.
//   TRANS=1 (GEMM1): A[e][k] = Hb[k][e]  (reg-prefetch scalar cols -> ds_write)
//   TRANS=0 (GEMM2): A[n][k] = Hb[n][k]  (global_load_lds)
//   B always global_load_lds.  Bt is [128][8192] bf16 (k-contiguous).
//   Partials stored bf16: part[sk][row][col].
// LDS layout: [128 rows][8 chunks x 16B]; slot s of row r holds k-chunk
// s^(r&7); frag read at kchunk kc uses slot kc^(r&7).
// ---------------------------------------------------------------------------
template <int TRANS>
__global__ __launch_bounds__(256) void gemm_sk(const unsigned short* __restrict__ Hb,
                                               const unsigned short* __restrict__ Bt,
                                               unsigned short* __restrict__ part) {
    __shared__ alignas(16) unsigned short As[2][8192];
    __shared__ alignas(16) unsigned short Bs[2][8192];

    const int t    = threadIdx.x;
    const int lane = t & 63;
    const int wid  = t >> 6;
    const int wr   = (wid >> 1) * 64;
    const int wc   = (wid & 1) * 64;
    const size_t mbase = (size_t)blockIdx.x * 128;
    const int kbase = blockIdx.y * 1024;

    const int rloc8 = lane >> 3;                 // 0..7
    const int schnk = (lane & 7) ^ rloc8;        // pre-swizzled source chunk
    const int c  = t & 127;                      // TRANS=1 A column
    const int kq = t >> 7;

    f32x4 acc[4][4];
#pragma unroll
    for (int m = 0; m < 4; ++m)
#pragma unroll
        for (int n = 0; n < 4; ++n)
#pragma unroll
            for (int i = 0; i < 4; ++i) acc[m][n][i] = 0.f;

    auto stageB = [&](int p, int k0) {
#pragma unroll
        for (int q = 0; q < 4; ++q) {
            const int i = wid * 4 + q;
            gload16(Bt + (size_t)(i * 8 + rloc8) * 8192 + k0 + schnk * 8,
                    (char*)Bs[p] + i * 1024);
        }
    };
    auto stageA0 = [&](int p, int k0) {
#pragma unroll
        for (int q = 0; q < 4; ++q) {
            const int i = wid * 4 + q;
            gload16(Hb + (mbase + i * 8 + rloc8) * 8192 + k0 + schnk * 8,
                    (char*)As[p] + i * 1024);
        }
    };
    auto loadA1 = [&](int k0, ushort4* r) {
        const unsigned short* base = Hb + mbase + c;
#pragma unroll
        for (int j = 0; j < 8; ++j) {
            const int kk = k0 + (j * 2 + kq) * 4;
            r[j].x = base[(size_t)(kk + 0) * 8192];
            r[j].y = base[(size_t)(kk + 1) * 8192];
            r[j].z = base[(size_t)(kk + 2) * 8192];
            r[j].w = base[(size_t)(kk + 3) * 8192];
        }
    };
    auto writeA1 = [&](int p, const ushort4* r) {
#pragma unroll
        for (int j = 0; j < 8; ++j)
            *(ushort4*)((char*)As[p] + c * 128 + (((j ^ (c & 7)) << 4) + kq * 8)) = r[j];
    };
    auto compute = [&](int p) {
        const char* asb = (const char*)As[p];
        const char* bsb = (const char*)Bs[p];
#pragma unroll
        for (int ks = 0; ks < 2; ++ks) {
            const int kch = ks * 4 + (lane >> 4);
            bf16x8 a[4], b[4];
#pragma unroll
            for (int m = 0; m < 4; ++m) {
                const int row = wr + m * 16 + (lane & 15);
                a[m] = *(const bf16x8*)(asb + row * 128 + ((kch ^ (row & 7)) << 4));
            }
#pragma unroll
            for (int n = 0; n < 4; ++n) {
                const int row = wc + n * 16 + (lane & 15);
                b[n] = *(const bf16x8*)(bsb + row * 128 + ((kch ^ (row & 7)) << 4));
            }
#pragma unroll
            for (int m = 0; m < 4; ++m)
#pragma unroll
                for (int n = 0; n < 4; ++n)
                    acc[m][n] = __builtin_amdgcn_mfma_f32_16x16x32_bf16(a[m], b[n], acc[m][n], 0, 0, 0);
        }
    };

    if (TRANS == 0) {
        stageB(0, kbase);
        stageA0(0, kbase);
        for (int tt = 0; tt < 16; ++tt) {
            const int p = tt & 1;
            if (tt < 15) {
                stageB(p ^ 1, kbase + (tt + 1) * 64);
                stageA0(p ^ 1, kbase + (tt + 1) * 64);
                asm volatile("s_waitcnt vmcnt(8)" ::: "memory");
            } else {
                asm volatile("s_waitcnt vmcnt(0)" ::: "memory");
            }
            __builtin_amdgcn_s_barrier();
            asm volatile("" ::: "memory");
            compute(p);
            asm volatile("s_waitcnt lgkmcnt(0)" ::: "memory");
            __builtin_amdgcn_s_barrier();
            asm volatile("" ::: "memory");
        }
    } else {
        ushort4 rA[8], rB2[8];
        stageB(0, kbase);
        loadA1(kbase, rA);
        for (int tt = 0; tt < 16; tt += 2) {
            // ---- tile tt (buffers 0) ----
            stageB(1, kbase + (tt + 1) * 64);
            loadA1(kbase + (tt + 1) * 64, rB2);
            writeA1(0, rA);        // auto-wait on rA => older B(tt) also landed
            asm volatile("s_waitcnt vmcnt(36) lgkmcnt(0)" ::: "memory");
            __builtin_amdgcn_s_barrier();
            asm volatile("" ::: "memory");
            compute(0);
            asm volatile("s_waitcnt lgkmcnt(0)" ::: "memory");
            __builtin_amdgcn_s_barrier();
            asm volatile("" ::: "memory");
            // ---- tile tt+1 (buffers 1) ----
            if (tt + 2 < 16) {
                stageB(0, kbase + (tt + 2) * 64);
                loadA1(kbase + (tt + 2) * 64, rA);
                writeA1(1, rB2);
                asm volatile("s_waitcnt vmcnt(36) lgkmcnt(0)" ::: "memory");
            } else {
                writeA1(1, rB2);
                asm volatile("s_waitcnt vmcnt(0) lgkmcnt(0)" ::: "memory");
            }
            __builtin_amdgcn_s_barrier();
            asm volatile("" ::: "memory");
            compute(1);
            asm volatile("s_waitcnt lgkmcnt(0)" ::: "memory");
            __builtin_amdgcn_s_barrier();
            asm volatile("" ::: "memory");
        }
    }

    unsigned short* po = part + ((size_t)blockIdx.y * 8192 + mbase) * 128;
#pragma unroll
    for (int m = 0; m < 4; ++m)
#pragma unroll
        for (int n = 0; n < 4; ++n)
#pragma unroll
            for (int r = 0; r < 4; ++r) {
                const int row = wr + m * 16 + (lane >> 4) * 4 + r;
                const int col = wc + n * 16 + (lane & 15);
                po[(size_t)row * 128 + col] = f2bf(acc[m][n][r]);
            }
}

// ---------------------------------------------------------------------------
// Reduce 8 bf16 split-K partials of GEMM1, scale by de_inv, X2t[d][e] bf16.
// ---------------------------------------------------------------------------
__global__ __launch_bounds__(256) void reduce1(const unsigned short* __restrict__ part,
                                               const float* __restrict__ de_inv,
                                               unsigned short* __restrict__ X2t) {
    const int idx = blockIdx.x * 256 + threadIdx.x;   // 262144
    const int d   = idx & 127;
    const int e0  = (idx >> 7) * 4;
    ushort4 o;
#pragma unroll
    for (int i = 0; i < 4; ++i) {
        const size_t base = (size_t)(e0 + i) * 128 + d;
        float s = 0.f;
#pragma unroll
        for (int sk = 0; sk < 8; ++sk) s += b2f(part[base + (size_t)sk * 1048576]);
        ((unsigned short*)&o)[i] = f2bf(s * de_inv[e0 + i]);
    }
    *(ushort4*)&X2t[(size_t)d * 8192 + e0] = o;
}

// ---------------------------------------------------------------------------
// Reduce 8 bf16 split-K partials of GEMM2 -> fp32 output (dv_is folded).
// ---------------------------------------------------------------------------
__global__ __launch_bounds__(256) void reduce2(const unsigned short* __restrict__ part,
                                               float* __restrict__ out) {
    const int idx = blockIdx.x * 256 + threadIdx.x;   // 262144, 4 outputs each
    f32x4 s;
    s[0] = 0.f; s[1] = 0.f; s[2] = 0.f; s[3] = 0.f;
#pragma unroll
    for (int sk = 0; sk < 8; ++sk) {
        ushort4 v = *(const ushort4*)&part[(size_t)sk * 1048576 + idx * 4];
        s[0] += b2f(v.x); s[1] += b2f(v.y); s[2] += b2f(v.z); s[3] += b2f(v.w);
    }
    ((f32x4*)out)[idx] = s;
}

// ---------------------------------------------------------------------------
// Workspace layout (bytes):
//   [0,        16777216)   split-K partials bf16 [8][8192][128]  (16 MB)
//                          (first 8 MB aliased as colpart bf16 [512][8192],
//                           dead after fin_fbt)
//   [16777216, +32768)     de_inv
//   [16809984, +2097152)   Fbt bf16 [128][8192]
//   [18907136, +2097152)   X2t bf16 [128][8192]
//   [21004288, +134217728) Hb  bf16 [8192][8192]  (dv_is-scaled)
// total ~149 MB
// ---------------------------------------------------------------------------
extern "C" void kernel_launch(void* const* d_in, const int* in_sizes, int n_in,
                              void* d_out, int out_size, void* d_ws, size_t ws_size,
                              hipStream_t stream) {
    const float* H = (const float*)d_in[0];
    const float* F = (const float*)d_in[1];
    float* out = (float*)d_out;
    char* ws = (char*)d_ws;

    unsigned short* part   = (unsigned short*)(ws);
    unsigned short* colpart= (unsigned short*)(ws);
    float* de_inv          = (float*)(ws + 16777216);
    unsigned short* Fbt    = (unsigned short*)(ws + 16809984);
    unsigned short* X2t    = (unsigned short*)(ws + 18907136);
    unsigned short* Hb     = (unsigned short*)(ws + 21004288);

    deg_convert <<<512, 256, 0, stream>>>(H, Hb, colpart);
    fin_fbt     <<<1280, 256, 0, stream>>>(colpart, F, de_inv, Fbt);
    gemm_sk<1>  <<<dim3(64, 8), 256, 0, stream>>>(Hb, Fbt, part);
    reduce1     <<<1024, 256, 0, stream>>>(part, de_inv, X2t);
    gemm_sk<0>  <<<dim3(64, 8), 256, 0, stream>>>(Hb, X2t, part);
    reduce2     <<<1024, 256, 0, stream>>>(part, out);
}